// Round 2
// baseline (92.227 us; speedup 1.0000x reference)
//
#include <hip/hip_runtime.h>

// Problem constants (from reference)
constexpr int B = 128, T = 12, V = 512, P = 40;
constexpr int CHUNKS = 8;        // V split across 8 blocks per batch
constexpr int VPB = V / CHUNKS;  // 64 v's per block, 4 threads per v
#define MAP_THRESH 0.5f
#define DIS_THRESH 1.0f
#define MASK_FILL  1000000.0f

// Lessons: R4 — agent-scope fences ~90 us, never. R6/R8 — device-scope atomic
// RMWs to single locations are cheap AND coherent cross-XCD. R9: single
// dispatch; cross-block data via atomic RMW (exch) + agent-scope loads.
// R10 (THIS SESSION): "last-writer proceeds" WITHOUT a guaranteed waiter is
// RACY — relaxed RMWs to different addresses carry no cross-XCD visibility
// order, so possibly NO block sees all-valid and part[b] is never written
// (tripwire caught it). Correct structure: designated block SPINS (guaranteed
// progress), other blocks get a one-shot readback FAST PATH and run the
// idempotent phase B/C only if they already see everything valid.

// transform: x = l*30 - 15 ; y = l*60 - 30  (two-step rounding, no FMA, matches np)
__device__ __forceinline__ float txf(float l) { return __fadd_rn(__fmul_rn(l, 30.0f), -15.0f); }
__device__ __forceinline__ float tyf(float l) { return __fadd_rn(__fmul_rn(l, 60.0f), -30.0f); }

// block-uniform float -> SGPR
__device__ __forceinline__ float rfl(float x) {
    return __int_as_float(__builtin_amdgcn_readfirstlane(__float_as_int(x)));
}

__device__ __forceinline__ unsigned long long ld_agent_u64(const unsigned long long* p) {
    return __hip_atomic_load(p, __ATOMIC_RELAXED, __HIP_MEMORY_SCOPE_AGENT);
}

#define FIXED_SCALE 1099511627776.0   /* 2^40 */
#define PART_BIAS   (1ULL << 45)

// packed min slot: ((bits(sd)+1) << 32) | v.  bits+1 is order-preserving for
// sd>=0 and makes high32>=1, so u64 order == (val, first-idx) rule and the
// value 0 / poison 0xAA.. / any low32>=512 are recognizably invalid.
__device__ __forceinline__ bool slot_valid(unsigned long long x) {
    return ((x & 0xffffffffULL) < (unsigned long long)V) &&
           (((x >> 32) - 1ULL) <= 0x7F800000ULL) && ((x >> 32) != 0ULL);
}
__device__ __forceinline__ bool part_valid(unsigned long long x) {
    return x >= PART_BIAS && x < (PART_BIAS << 1);
}

// Single kernel, grid = B*CHUNKS = 1024 blocks x 256.
// Phase A (all blocks): per-t min over 64 v's (float butterfly + ballot for
//   the argmin index — lane order == v order, so ctz(ballot) = first index)
//   -> packed u64 atomicExch into this chunk's slot.
// Readback: designated block (c==7) SPINS until its b's 96 slots are valid
//   (guaranteed progress). Other blocks one-shot read; all-valid -> run the
//   idempotent phase B too (fast path), else exit.
// Phase B: cross-chunk u64 min, intersections, weighted sum -> biased
//   fixed-point atomicExch into part[b].
// Phase C: designated block (0,7) spins on part[0..127]; other phase-B
//   completers one-shot read and finalize only if all-valid. out idempotent.
__global__ __launch_bounds__(256) void k_all(
    const float* __restrict__ ego,     // B,T,2
    const float* __restrict__ lanes,   // B,V,P,2
    const float* __restrict__ scores,  // B,V,3
    const float* __restrict__ weight,  // B,T
    unsigned long long* __restrict__ ws_min,  // B*T*CHUNKS slots
    unsigned long long* __restrict__ part,    // B
    float* __restrict__ out)
{
    const int blk = blockIdx.x;
    const int b = blk / CHUNKS, c = blk % CHUNKS;
    const int tid = threadIdx.x;
    const int wid = tid >> 6, lane = tid & 63;
    const int pp = tid & 3;    // float4s {pp, 4+pp, 8+pp, 12+pp, 16+pp}
    const int v = c * VPB + (tid >> 2);

    // ---- issue ALL global loads first (unconditional -> fully pipelined) ----
    const float sc = scores[(size_t)(b * V + v) * 3 + 2];
    const float4* lp = (const float4*)(lanes + (size_t)(b * V + v) * P * 2);
    float4 f0 = lp[pp];
    float4 f1 = lp[4 + pp];
    float4 f2 = lp[8 + pp];
    float4 f3 = lp[12 + pp];
    float4 f4 = lp[16 + pp];

    // ---- wave-parallel ego cumsum (overlaps the lane loads above) ----
    __shared__ float s_px[T + 1], s_py[T + 1];
    __shared__ float s_w[T];
    __shared__ int   s_cross[T];
    __shared__ int   s_nv, s_nv2;
    if (wid == 0) {
        float e = (lane < 2 * T) ? ego[b * 2 * T + lane] : 0.f;
        float cx = 0.f, cy = 0.f;
#pragma unroll
        for (int k = 0; k < T; ++k) {  // exact left-to-right fp32 cumsum
            float vx = __shfl(e, 2 * k);
            float vy = __shfl(e, 2 * k + 1);
            if (k <= lane) { cx = __fadd_rn(cx, vx); cy = __fadd_rn(cy, vy); }
        }
        if (lane == 0) { s_px[0] = 0.f; s_py[0] = 0.f; }
        if (lane < T)  { s_px[lane + 1] = cx; s_py[lane + 1] = cy; }
    } else if (wid == 1) {
        if (lane < T) s_w[lane] = weight[b * T + lane];
        else if (lane < 2 * T) s_cross[lane - T] = 0;
        else if (lane == 2 * T) s_nv = 0;
        else if (lane == 2 * T + 1) s_nv2 = 0;
    }
    __syncthreads();

    // block-uniform trajectory -> SGPRs
    float px[T], py[T];
#pragma unroll
    for (int t = 0; t < T; ++t) { px[t] = rfl(s_px[t + 1]); py[t] = rfl(s_py[t + 1]); }

    float minsq[T];
#pragma unroll
    for (int t = 0; t < T; ++t) minsq[t] = 3.4e38f;
    const float4 fr[5] = {f0, f1, f2, f3, f4};
#pragma unroll
    for (int j = 0; j < 5; ++j) {
        float x0 = txf(fr[j].x), y0 = tyf(fr[j].y);
        float x1 = txf(fr[j].z), y1 = tyf(fr[j].w);
#pragma unroll
        for (int t = 0; t < T; ++t) {
            float dxa = __fsub_rn(px[t], x0);
            float dya = __fsub_rn(py[t], y0);
            float d2a = __fadd_rn(__fmul_rn(dxa, dxa), __fmul_rn(dya, dya));
            float dxb = __fsub_rn(px[t], x1);
            float dyb = __fsub_rn(py[t], y1);
            float d2b = __fadd_rn(__fmul_rn(dxb, dxb), __fmul_rn(dyb, dyb));
            // fmin is exact: grouping change is value-identical, lets v_min3 fuse
            minsq[t] = fminf(minsq[t], fminf(d2a, d2b));
        }
    }
    if (sc < MAP_THRESH) {  // masked: all P points are exactly (1e6, 1e6)
#pragma unroll
        for (int t = 0; t < T; ++t) {
            float dx = __fsub_rn(px[t], MASK_FILL);
            float dy = __fsub_rn(py[t], MASK_FILL);
            minsq[t] = __fadd_rn(__fmul_rn(dx, dx), __fmul_rn(dy, dy));
        }
    }

    // combine the 4 point-chunks of this v (adjacent lanes)
#pragma unroll
    for (int t = 0; t < T; ++t) {
        minsq[t] = fminf(minsq[t], __shfl_xor(minsq[t], 1));
        minsq[t] = fminf(minsq[t], __shfl_xor(minsq[t], 2));
    }

    // sqrt monotone under RN: sqrt(min)==min(sqrt). Float-only butterfly over
    // the 16 v-slots (1 bpermute/step), then ballot+ctz for the argmin:
    // lane order == v order, so lowest set lane == first (smallest) v.
    // (Compare POST-sqrt values: pre-sqrt compare could flip tie-breaks when
    // two distinct d2 round to the same sqrt.)
    __shared__ unsigned long long wmin[T][4];
#pragma unroll
    for (int t = 0; t < T; ++t) {
        float s = sqrtf(minsq[t]);
        float m = s;
#pragma unroll
        for (int d = 4; d <= 32; d <<= 1) m = fminf(m, __shfl_xor(m, d));
        unsigned long long ball = __ballot(s == m);   // nonempty by construction
        int l = __builtin_ctzll(ball);                // uniform scalar
        unsigned vmin = (unsigned)(c * VPB) + (unsigned)(wid << 4) + ((unsigned)l >> 2);
        if (lane == 0)
            wmin[t][wid] = (((unsigned long long)__float_as_uint(m) + 1ULL) << 32) | vmin;
    }
    __syncthreads();
    if (tid < T) {
        unsigned long long m = wmin[tid][0];
#pragma unroll
        for (int w = 1; w < 4; ++w) m = (wmin[tid][w] < m) ? wmin[tid][w] : m;
        // device-scope RMW -> coherent at L2 coherence point, cross-XCD safe
        atomicExch(&ws_min[(b * T + tid) * CHUNKS + c], m);
    }
    __syncthreads();  // drains our exchs before the readback below

    // ---- readback: designated block spins (guaranteed), others one-shot ----
    __shared__ unsigned long long s_m[T][CHUNKS];
    if (tid < T * CHUNKS) {   // 96 lanes
        int t = tid >> 3, cc = tid & 7;
        const unsigned long long* p = &ws_min[(b * T + t) * CHUNKS + cc];
        unsigned long long x = ld_agent_u64(p);
        if (c == CHUNKS - 1) {  // designated: validity-gated spin
            while (!slot_valid(x)) { __builtin_amdgcn_s_sleep(2); x = ld_agent_u64(p); }
        } else if (!slot_valid(x)) {
            s_nv = 1;   // racy identical-value write: fine
        }
        s_m[t][cc] = x;
    }
    __syncthreads();
    if (s_nv) return;   // uniform; designated block never sets s_nv

    // ---------------- Phase B (designated + fast-path blocks; idempotent) ----------------
    __shared__ float s_md[T];
    __shared__ int   s_vm[T];
    __shared__ int   s_ok[T];
    if (tid < T) {
        unsigned long long m = s_m[tid][0];
#pragma unroll
        for (int cc = 1; cc < CHUNKS; ++cc)  // u64 min == (val, first-idx) rule
            m = (s_m[tid][cc] < m) ? s_m[tid][cc] : m;
        s_md[tid] = __uint_as_float((unsigned)((m >> 32) - 1ULL));
        int vw = (int)(m & 0xffffffffu);
        s_vm[tid] = vw;
        // masked lane -> all points identical -> det == 0 -> never intersects
        s_ok[tid] = (scores[(size_t)(b * V + vw) * 3 + 2] >= MAP_THRESH) ? 1 : 0;
    }
    __syncthreads();

    // 12 x 39 intersection tests (lanes/scores are pristine inputs: plain loads)
    for (int w = tid; w < T * (P - 1); w += 256) {
        int t = w / (P - 1), p = w % (P - 1);
        if (!s_ok[t]) continue;
        const float* lq = lanes + (size_t)(b * V + s_vm[t]) * P * 2 + (size_t)p * 2;
        float bx0 = txf(lq[0]), by0 = tyf(lq[1]);
        float bx1 = txf(lq[2]), by1 = tyf(lq[3]);
        float sx = s_px[t],     sy = s_py[t];      // starts[t]
        float ex = s_px[t + 1], ey = s_py[t + 1];  // pred[t]
        float d1x = __fsub_rn(ex, sx),  d1y = __fsub_rn(ey, sy);
        float d2x = __fsub_rn(bx1, bx0), d2y = __fsub_rn(by1, by0);
        float det = __fsub_rn(__fmul_rn(d1x, d2y), __fmul_rn(d2x, d1y));
        if (det != 0.0f) {
            float dx = __fsub_rn(bx0, sx), dy = __fsub_rn(by0, sy);
            float t1 = __fdiv_rn(__fsub_rn(__fmul_rn(dx, d2y), __fmul_rn(dy, d2x)), det);
            float t2 = __fdiv_rn(__fsub_rn(__fmul_rn(dx, d1y), __fmul_rn(dy, d1x)), det);
            if (t1 >= 0.f && t1 <= 1.f && t2 >= 0.f && t2 <= 1.f)
                atomicOr(&s_cross[t], 1);  // LDS atomic, block-local
        }
    }
    __syncthreads();

    if (tid == 0) {
        float sum = 0.f;
        int crossed = 0;
#pragma unroll
        for (int t = 0; t < T; ++t) {
            crossed |= s_cross[t];  // cumsum(intersect) >= 1
            float md = s_md[t];
            float l = (md <= DIS_THRESH) ? __fsub_rn(DIS_THRESH, md) : 0.f;
            if (crossed) l = 0.f;
            sum = __fadd_rn(sum, __fmul_rn(l, s_w[t]));
        }
        // biased fixed-point partial: q + 2^45 in [2^45, 2^46) -> poison/zero invalid
        unsigned long long q = (unsigned long long)((double)sum * FIXED_SCALE + 0.5);
        atomicExch(&part[b], q + PART_BIAS);
    }
    __syncthreads();  // drain the part exch before the readback

    // ---- part readback: designated (0,7) spins, others one-shot ----
    __shared__ unsigned long long s_part[B];
    if (tid < B) {
        const unsigned long long* p = &part[tid];
        unsigned long long x = ld_agent_u64(p);
        if (b == 0 && c == CHUNKS - 1) {  // designated finalizer: guaranteed
            while (!part_valid(x)) { __builtin_amdgcn_s_sleep(2); x = ld_agent_u64(p); }
        } else if (!part_valid(x)) {
            s_nv2 = 1;
        }
        s_part[tid] = x;
    }
    __syncthreads();
    if (s_nv2) return;   // uniform; designated finalizer never sets s_nv2

    // ---------------- Phase C: exact integer sum of 128 partials ----------------
    if (tid == 0) {
        unsigned long long tot = 0ULL;
#pragma unroll
        for (int i = 0; i < B; ++i) tot += s_part[i];   // exact integer sum
        tot -= (unsigned long long)B * PART_BIAS;
        out[0] = (float)((double)tot * (1.0 / FIXED_SCALE) / (double)(B * T));
    }
}

extern "C" void kernel_launch(void* const* d_in, const int* in_sizes, int n_in,
                              void* d_out, int out_size, void* d_ws, size_t ws_size,
                              hipStream_t stream) {
    const float* ego    = (const float*)d_in[0];  // B,T,2
    const float* lanes  = (const float*)d_in[1];  // B,V,P,2
    const float* scores = (const float*)d_in[2];  // B,V,3
    const float* weight = (const float*)d_in[3];  // B,T
    float* out = (float*)d_out;

    unsigned long long* ws_min = (unsigned long long*)d_ws;        // B*T*CHUNKS u64
    unsigned long long* part   = ws_min + (size_t)B * T * CHUNKS;  // B u64

    k_all<<<B * CHUNKS, 256, 0, stream>>>(ego, lanes, scores, weight, ws_min, part, out);
}

// Round 3
// 84.685 us; speedup vs baseline: 1.0891x; 1.0891x over previous
//
#include <hip/hip_runtime.h>

// Problem constants (from reference)
constexpr int B = 128, T = 12, V = 512, P = 40;
constexpr int CHUNKS = 8;        // V split across 8 blocks per batch
constexpr int VPB = V / CHUNKS;  // 64 v's per block, 4 threads per v
#define MAP_THRESH 0.5f
#define DIS_THRESH 1.0f
#define MASK_FILL  1000000.0f

// Lessons: R4 — agent-scope fences ~90 us, never. R6/R8 — device-scope atomic
// RMWs to single locations are cheap AND coherent cross-XCD. R9: single
// dispatch; cross-block data via atomic RMW (exch) + agent-scope loads with
// validity-gated spin in ONE designated block per b.
// R10: "last-writer proceeds" without a guaranteed waiter is RACY (tripwire).
// R11: hybrid fast path (all blocks drain vmcnt + readback + idempotent
// phase B) REGRESSED 85.8->92.2: the extra __syncthreads after the exch waits
// ~900cy for device-scope ack in EVERY block, and redundant phase B fattens
// the tail. Producers must EXIT immediately after the exch (write completes
// in flight). This file: baseline protocol + slimmed phase A only
// (float butterfly 1-bpermute/step, ballot+ctz argmin, v_min3 grouping).

// transform: x = l*30 - 15 ; y = l*60 - 30  (two-step rounding, no FMA, matches np)
__device__ __forceinline__ float txf(float l) { return __fadd_rn(__fmul_rn(l, 30.0f), -15.0f); }
__device__ __forceinline__ float tyf(float l) { return __fadd_rn(__fmul_rn(l, 60.0f), -30.0f); }

// block-uniform float -> SGPR
__device__ __forceinline__ float rfl(float x) {
    return __int_as_float(__builtin_amdgcn_readfirstlane(__float_as_int(x)));
}

__device__ __forceinline__ unsigned long long ld_agent_u64(const unsigned long long* p) {
    return __hip_atomic_load(p, __ATOMIC_RELAXED, __HIP_MEMORY_SCOPE_AGENT);
}

#define FIXED_SCALE 1099511627776.0   /* 2^40 */
#define PART_BIAS   (1ULL << 45)

// packed min slot: ((bits(sd)+1) << 32) | v.  bits+1 is order-preserving for
// sd>=0 and makes high32>=1, so u64 order == (val, first-idx) rule and the
// value 0 / poison 0xAA.. / any low32>=512 are recognizably invalid.
__device__ __forceinline__ bool slot_valid(unsigned long long x) {
    return ((x & 0xffffffffULL) < (unsigned long long)V) &&
           (((x >> 32) - 1ULL) <= 0x7F800000ULL) && ((x >> 32) != 0ULL);
}
__device__ __forceinline__ bool part_valid(unsigned long long x) {
    return x >= PART_BIAS && x < (PART_BIAS << 1);
}

// Single kernel, grid = B*CHUNKS = 1024 blocks x 256.
// Phase A (all blocks): per-t min over 64 v's (float butterfly + ballot/ctz
//   argmin — lane order == v order) -> packed u64 atomicExch into chunk slot.
//   Producers (c != 7) exit immediately; exch completes in flight.
// Phase B (c==7 block per b): validity-spin on the 8 chunk slots per t,
//   intersections, weighted sum -> biased fixed-point atomicExch into part[b].
// Phase C (block b==0,c==7): lanes spin-read part[0..127], exact u64 sum, out.
__global__ __launch_bounds__(256) void k_all(
    const float* __restrict__ ego,     // B,T,2
    const float* __restrict__ lanes,   // B,V,P,2
    const float* __restrict__ scores,  // B,V,3
    const float* __restrict__ weight,  // B,T
    unsigned long long* __restrict__ ws_min,  // B*T*CHUNKS slots
    unsigned long long* __restrict__ part,    // B
    float* __restrict__ out)
{
    const int blk = blockIdx.x;
    const int b = blk / CHUNKS, c = blk % CHUNKS;
    const int tid = threadIdx.x;
    const int wid = tid >> 6, lane = tid & 63;
    const int pp = tid & 3;    // float4s {pp, 4+pp, 8+pp, 12+pp, 16+pp}
    const int v = c * VPB + (tid >> 2);

    // ---- issue ALL global loads first (unconditional -> fully pipelined) ----
    const float sc = scores[(size_t)(b * V + v) * 3 + 2];
    const float4* lp = (const float4*)(lanes + (size_t)(b * V + v) * P * 2);
    float4 f0 = lp[pp];
    float4 f1 = lp[4 + pp];
    float4 f2 = lp[8 + pp];
    float4 f3 = lp[12 + pp];
    float4 f4 = lp[16 + pp];

    // ---- wave-parallel ego cumsum (overlaps the lane loads above) ----
    __shared__ float s_px[T + 1], s_py[T + 1];
    __shared__ float s_w[T];
    __shared__ int   s_cross[T];
    if (wid == 0) {
        float e = (lane < 2 * T) ? ego[b * 2 * T + lane] : 0.f;
        float cx = 0.f, cy = 0.f;
#pragma unroll
        for (int k = 0; k < T; ++k) {  // exact left-to-right fp32 cumsum
            float vx = __shfl(e, 2 * k);
            float vy = __shfl(e, 2 * k + 1);
            if (k <= lane) { cx = __fadd_rn(cx, vx); cy = __fadd_rn(cy, vy); }
        }
        if (lane == 0) { s_px[0] = 0.f; s_py[0] = 0.f; }
        if (lane < T)  { s_px[lane + 1] = cx; s_py[lane + 1] = cy; }
    } else if (wid == 1) {
        if (lane < T) s_w[lane] = weight[b * T + lane];
        else if (lane < 2 * T) s_cross[lane - T] = 0;
    }
    __syncthreads();

    // block-uniform trajectory -> SGPRs
    float px[T], py[T];
#pragma unroll
    for (int t = 0; t < T; ++t) { px[t] = rfl(s_px[t + 1]); py[t] = rfl(s_py[t + 1]); }

    float minsq[T];
#pragma unroll
    for (int t = 0; t < T; ++t) minsq[t] = 3.4e38f;
    const float4 fr[5] = {f0, f1, f2, f3, f4};
#pragma unroll
    for (int j = 0; j < 5; ++j) {
        float x0 = txf(fr[j].x), y0 = tyf(fr[j].y);
        float x1 = txf(fr[j].z), y1 = tyf(fr[j].w);
#pragma unroll
        for (int t = 0; t < T; ++t) {
            float dxa = __fsub_rn(px[t], x0);
            float dya = __fsub_rn(py[t], y0);
            float d2a = __fadd_rn(__fmul_rn(dxa, dxa), __fmul_rn(dya, dya));
            float dxb = __fsub_rn(px[t], x1);
            float dyb = __fsub_rn(py[t], y1);
            float d2b = __fadd_rn(__fmul_rn(dxb, dxb), __fmul_rn(dyb, dyb));
            // fmin is exact: grouping change is value-identical, lets v_min3 fuse
            minsq[t] = fminf(minsq[t], fminf(d2a, d2b));
        }
    }
    if (sc < MAP_THRESH) {  // masked: all P points are exactly (1e6, 1e6)
#pragma unroll
        for (int t = 0; t < T; ++t) {
            float dx = __fsub_rn(px[t], MASK_FILL);
            float dy = __fsub_rn(py[t], MASK_FILL);
            minsq[t] = __fadd_rn(__fmul_rn(dx, dx), __fmul_rn(dy, dy));
        }
    }

    // combine the 4 point-chunks of this v (adjacent lanes)
#pragma unroll
    for (int t = 0; t < T; ++t) {
        minsq[t] = fminf(minsq[t], __shfl_xor(minsq[t], 1));
        minsq[t] = fminf(minsq[t], __shfl_xor(minsq[t], 2));
    }

    // sqrt monotone under RN: sqrt(min)==min(sqrt). Float-only butterfly over
    // the 16 v-slots (1 bpermute/step), then ballot+ctz for the argmin:
    // lane order == v order, so lowest set lane == first (smallest) v.
    __shared__ unsigned long long wmin[T][4];
#pragma unroll
    for (int t = 0; t < T; ++t) {
        float s = sqrtf(minsq[t]);
        float m = s;
#pragma unroll
        for (int d = 4; d <= 32; d <<= 1) m = fminf(m, __shfl_xor(m, d));
        unsigned long long ball = __ballot(s == m);   // nonempty by construction
        int l = __builtin_ctzll(ball);                // uniform scalar
        unsigned vmin = (unsigned)(c * VPB) + (unsigned)(wid << 4) + ((unsigned)l >> 2);
        if (lane == 0)
            wmin[t][wid] = (((unsigned long long)__float_as_uint(m) + 1ULL) << 32) | vmin;
    }
    __syncthreads();
    if (tid < T) {
        unsigned long long m = wmin[tid][0];
#pragma unroll
        for (int w = 1; w < 4; ++w) m = (wmin[tid][w] < m) ? wmin[tid][w] : m;
        // device-scope RMW -> coherent at L2 coherence point, cross-XCD safe
        atomicExch(&ws_min[(b * T + tid) * CHUNKS + c], m);
    }

    if (c != CHUNKS - 1) return;   // uniform exit for producer-only blocks

    // ---------------- Phase B (one block per b) ----------------
    __shared__ unsigned long long s_m[T][CHUNKS];
    __shared__ float s_md[T];
    __shared__ int   s_vm[T];
    __shared__ int   s_ok[T];
    if (tid < T * CHUNKS) {   // 96 lanes: validity-gated spin on chunk slots
        int t = tid >> 3, cc = tid & 7;
        const unsigned long long* p = &ws_min[(b * T + t) * CHUNKS + cc];
        unsigned long long x = ld_agent_u64(p);
        while (!slot_valid(x)) { __builtin_amdgcn_s_sleep(2); x = ld_agent_u64(p); }
        s_m[t][cc] = x;
    }
    __syncthreads();
    if (tid < T) {
        unsigned long long m = s_m[tid][0];
#pragma unroll
        for (int cc = 1; cc < CHUNKS; ++cc)  // u64 min == (val, first-idx) rule
            m = (s_m[tid][cc] < m) ? s_m[tid][cc] : m;
        s_md[tid] = __uint_as_float((unsigned)((m >> 32) - 1ULL));
        int vw = (int)(m & 0xffffffffu);
        s_vm[tid] = vw;
        // masked lane -> all points identical -> det == 0 -> never intersects
        s_ok[tid] = (scores[(size_t)(b * V + vw) * 3 + 2] >= MAP_THRESH) ? 1 : 0;
    }
    __syncthreads();

    // 12 x 39 intersection tests (lanes/scores are pristine inputs: plain loads)
    for (int w = tid; w < T * (P - 1); w += 256) {
        int t = w / (P - 1), p = w % (P - 1);
        if (!s_ok[t]) continue;
        const float* lq = lanes + (size_t)(b * V + s_vm[t]) * P * 2 + (size_t)p * 2;
        float bx0 = txf(lq[0]), by0 = tyf(lq[1]);
        float bx1 = txf(lq[2]), by1 = tyf(lq[3]);
        float sx = s_px[t],     sy = s_py[t];      // starts[t]
        float ex = s_px[t + 1], ey = s_py[t + 1];  // pred[t]
        float d1x = __fsub_rn(ex, sx),  d1y = __fsub_rn(ey, sy);
        float d2x = __fsub_rn(bx1, bx0), d2y = __fsub_rn(by1, by0);
        float det = __fsub_rn(__fmul_rn(d1x, d2y), __fmul_rn(d2x, d1y));
        if (det != 0.0f) {
            float dx = __fsub_rn(bx0, sx), dy = __fsub_rn(by0, sy);
            float t1 = __fdiv_rn(__fsub_rn(__fmul_rn(dx, d2y), __fmul_rn(dy, d2x)), det);
            float t2 = __fdiv_rn(__fsub_rn(__fmul_rn(dx, d1y), __fmul_rn(dy, d1x)), det);
            if (t1 >= 0.f && t1 <= 1.f && t2 >= 0.f && t2 <= 1.f)
                atomicOr(&s_cross[t], 1);  // LDS atomic, block-local
        }
    }
    __syncthreads();

    if (tid == 0) {
        float sum = 0.f;
        int crossed = 0;
#pragma unroll
        for (int t = 0; t < T; ++t) {
            crossed |= s_cross[t];  // cumsum(intersect) >= 1
            float md = s_md[t];
            float l = (md <= DIS_THRESH) ? __fsub_rn(DIS_THRESH, md) : 0.f;
            if (crossed) l = 0.f;
            sum = __fadd_rn(sum, __fmul_rn(l, s_w[t]));
        }
        // biased fixed-point partial: q + 2^45 in [2^45, 2^46) -> poison/zero invalid
        unsigned long long q = (unsigned long long)((double)sum * FIXED_SCALE + 0.5);
        atomicExch(&part[b], q + PART_BIAS);
    }

    if (b != 0) return;   // uniform exit; only block (0, CHUNKS-1) finalizes

    // ---------------- Phase C: exact integer sum of 128 partials ----------------
    __shared__ unsigned long long s_part[B];
    if (tid < B) {
        const unsigned long long* p = &part[tid];
        unsigned long long x = ld_agent_u64(p);
        while (!part_valid(x)) { __builtin_amdgcn_s_sleep(2); x = ld_agent_u64(p); }
        s_part[tid] = x;
    }
    __syncthreads();
    if (tid == 0) {
        unsigned long long tot = 0ULL;
#pragma unroll
        for (int i = 0; i < B; ++i) tot += s_part[i];   // exact integer sum
        tot -= (unsigned long long)B * PART_BIAS;
        out[0] = (float)((double)tot * (1.0 / FIXED_SCALE) / (double)(B * T));
    }
}

extern "C" void kernel_launch(void* const* d_in, const int* in_sizes, int n_in,
                              void* d_out, int out_size, void* d_ws, size_t ws_size,
                              hipStream_t stream) {
    const float* ego    = (const float*)d_in[0];  // B,T,2
    const float* lanes  = (const float*)d_in[1];  // B,V,P,2
    const float* scores = (const float*)d_in[2];  // B,V,3
    const float* weight = (const float*)d_in[3];  // B,T
    float* out = (float*)d_out;

    unsigned long long* ws_min = (unsigned long long*)d_ws;        // B*T*CHUNKS u64
    unsigned long long* part   = ws_min + (size_t)B * T * CHUNKS;  // B u64

    k_all<<<B * CHUNKS, 256, 0, stream>>>(ego, lanes, scores, weight, ws_min, part, out);
}